// Round 10
// baseline (820.176 us; speedup 1.0000x reference)
//
#include <hip/hip_runtime.h>

#define NN 20000
#define EE 640000
#define TT 8
#define HF 64
#define AS 232     // LDS A-tile row stride (f16) in k_ru
#define ACS 104    // LDS A_c tile row stride (f16)
#define BSS 194    // LDS B-stage row stride (f16), gcd(97,32)=1
#define PBLK 5000  // prop blocks (4 nodes each)
#define TILE 2560  // edges per k_bin tile (250 tiles/step)
#define NBIN 250   // bins (both src and dst side)
#define BWID 80    // nodes per bin
#define ECAP 3072  // per-(step,bin) CSR capacity (mean 2560 + 10 sigma)
#define LCAP 24    // per-tile per-bin slot capacity (mean 10.2; spill path)
#define TB 2       // steps per edge-phase batch
#define SPCAP 4096 // per-step spill capacity

typedef _Float16 f16;
typedef unsigned int uint;
typedef unsigned char uchar;
typedef unsigned long long ull;
typedef __attribute__((ext_vector_type(8))) _Float16 half8;
typedef __attribute__((ext_vector_type(4))) float floatx4;

__device__ __forceinline__ float lo16f(uint v) { return (float)__builtin_bit_cast(f16, (unsigned short)(v & 0xffff)); }
__device__ __forceinline__ float hi16f(uint v) { return (float)__builtin_bit_cast(f16, (unsigned short)(v >> 16)); }
__device__ __forceinline__ uint pk16(float a, float b) {
    unsigned short ua = __builtin_bit_cast(unsigned short, (f16)a);
    unsigned short ub = __builtin_bit_cast(unsigned short, (f16)b);
    return (uint)ua | ((uint)ub << 16);
}

// ---------------- weight packs (once per launch) ----------------
__global__ __launch_bounds__(256) void k_prepW(
    const float* __restrict__ Wr, const float* __restrict__ Wu, const float* __restrict__ Wc,
    f16* __restrict__ Wp, f16* __restrict__ Wcp)
{
    int idx = blockIdx.x * 256 + threadIdx.x;
    if (idx < 8 * 7 * 64) {
        int lane = idx & 63;
        int kb = (idx >> 6) % 7;
        int nb = (idx >> 6) / 7;
        int col = nb * 16 + (lane & 15);
        int g = col >> 6, jj = col & 63;
        const float* W = (g == 0) ? Wr : Wu;
        half8 v;
        #pragma unroll
        for (int e = 0; e < 8; e++) {
            int k = kb * 32 + ((lane >> 4) << 3) + e;
            float val = 0.f;
            if (k < 192)      { int hop = k >> 6; int i = 2 + (k & 63); val = W[(hop * 66 + i) * 64 + jj]; }
            else if (k < 198) { int q = k - 192;  int hop = q >> 1;     val = W[(hop * 66 + (q & 1)) * 64 + jj]; }
            v[e] = (f16)val;
        }
        *(half8*)&Wp[(size_t)idx * 8] = v;
        return;
    }
    int idx2 = idx - 8 * 7 * 64;
    if (idx2 >= 12 * 3 * 64) return;
    int lane = idx2 & 63;
    int kb = (idx2 >> 6) % 3;
    int nbc = (idx2 >> 6) / 3;
    int col = nbc * 16 + (lane & 15);
    int mode = col >> 6, j = col & 63;
    half8 v;
    #pragma unroll
    for (int e = 0; e < 8; e++) {
        int k = kb * 32 + ((lane >> 4) << 3) + e;
        float val = 0.f;
        if (k < 66) {
            if (mode == 0)      val = Wc[(0 * 66 + k) * 64 + j] - Wc[(2 * 66 + k) * 64 + j];
            else if (mode == 1) val = Wc[(1 * 66 + k) * 64 + j];
            else                val = Wc[(2 * 66 + k) * 64 + j];
        }
        v[e] = (f16)val;
    }
    *(half8*)&Wcp[(size_t)idx2 * 8] = v;
}

// ---------------- pack all x into f16x2 (once per launch) ----------------
__global__ __launch_bounds__(256) void k_pack(
    const float* __restrict__ x, uint* __restrict__ xf)
{
    int idx = blockIdx.x * 256 + threadIdx.x;
    if (idx < TT * NN) xf[idx] = pk16(x[2 * idx], x[2 * idx + 1]);
}

// ---------------- binning: tile-private slot regions, zero hot global atomics ----------------
// dst entry: (d<<16|s, w_f32) -> dslot[tl*250+tile][bin][LCAP]
// src entry: (w_f16<<16|s)    -> sslot[tl*250+tile][bin][LCAP]
// overflow (rare, ~10/step): global spill lists dsp/ssp with one atomic each.
__global__ __launch_bounds__(256) void k_bin(
    const int* __restrict__ eidx, const float* __restrict__ eatt, int t0,
    ull* __restrict__ dslot, uchar* __restrict__ dcnt_,
    uint* __restrict__ sslot, uchar* __restrict__ scnt_,
    ull* __restrict__ dsp, int* __restrict__ spn,
    uint* __restrict__ ssp, int* __restrict__ ssn)
{
    __shared__ uint2 buf[NBIN][LCAP];    // 48000 B
    __shared__ uint  sbl[NBIN][LCAP];    // 24000 B
    __shared__ int lcnt[NBIN], scnt[NBIN];
    int tid = threadIdx.x;
    if (tid < NBIN) { lcnt[tid] = 0; scnt[tid] = 0; }
    __syncthreads();
    int tl = blockIdx.x / 250, tile = blockIdx.x % 250;
    const int*   src = eidx + (size_t)(t0 + tl) * 2 * EE + tile * TILE;
    const int*   dst = src + EE;
    const float* w   = eatt + (size_t)(t0 + tl) * EE + tile * TILE;
    #pragma unroll
    for (int i = 0; i < TILE / 256; i++) {
        int e = i * 256 + tid;
        int s = __builtin_nontemporal_load(&src[e]);
        int d = __builtin_nontemporal_load(&dst[e]);
        float wv = __builtin_nontemporal_load(&w[e]);
        // dst side
        int bin = d / BWID;
        int p = atomicAdd(&lcnt[bin], 1);
        if (p < LCAP) buf[bin][p] = make_uint2(((uint)d << 16) | (uint)s, __float_as_uint(wv));
        else {
            int gp = atomicAdd(&spn[tl], 1);
            if (gp < SPCAP) dsp[(size_t)tl * SPCAP + gp] =
                (ull)__float_as_uint(wv) << 32 | (((uint)d << 16) | (uint)s);
        }
        // src side (deg)
        int sbin = s / BWID;
        uint sent = (pk16(wv, 0.f) << 16) | (uint)s;
        int sq = atomicAdd(&scnt[sbin], 1);
        if (sq < LCAP) sbl[sbin][sq] = sent;
        else {
            int gp = atomicAdd(&ssn[tl], 1);
            if (gp < SPCAP) ssp[(size_t)tl * SPCAP + gp] = sent;
        }
    }
    __syncthreads();
    // dense private flush (nontemporal; garbage beyond counts never read)
    size_t base = (size_t)blockIdx.x * (NBIN * LCAP);
    const ull* bufl = (const ull*)&buf[0][0];
    for (int idx = tid; idx < NBIN * LCAP; idx += 256)
        __builtin_nontemporal_store(bufl[idx], &dslot[base + idx]);
    const uint* sbll = &sbl[0][0];
    for (int idx = tid; idx < NBIN * LCAP; idx += 256)
        __builtin_nontemporal_store(sbll[idx], &sslot[base + idx]);
    if (tid < NBIN) {
        dcnt_[blockIdx.x * 256 + tid] = (uchar)(lcnt[tid] < LCAP ? lcnt[tid] : LCAP);
        scnt_[blockIdx.x * 256 + tid] = (uchar)(scnt[tid] < LCAP ? scnt[tid] : LCAP);
    }
}

// ---------------- deg reduce: per src-bin over tile chunks + spills ----------------
__global__ __launch_bounds__(256) void k_degred(
    const uint* __restrict__ sslot, const uchar* __restrict__ scnt_,
    const uint* __restrict__ ssp, const int* __restrict__ ssn,
    float* __restrict__ dinv)
{
    __shared__ float dacc[BWID];
    __shared__ uchar cs[256];
    int tl = blockIdx.x / NBIN, b = blockIdx.x % NBIN, tid = threadIdx.x;
    if (tid < BWID) dacc[tid] = 0.f;
    if (tid < 256) cs[tid] = (tid < 250) ? scnt_[(tl * 250 + tid) * 256 + b] : 0;
    __syncthreads();
    for (int idx = tid; idx < 250 * LCAP; idx += 256) {
        int t = idx / LCAP, p = idx % LCAP;
        if (p < (int)cs[t]) {
            uint e = __builtin_nontemporal_load(
                &sslot[((size_t)(tl * 250 + t) * NBIN + b) * LCAP + p]);
            atomicAdd(&dacc[(e & 0xffff) - b * BWID], hi16f(e));
        }
    }
    int nsp = ssn[tl]; if (nsp > SPCAP) nsp = SPCAP;
    for (int i = tid; i < nsp; i += 256) {
        uint e = ssp[(size_t)tl * SPCAP + i];
        int s = e & 0xffff;
        if (s / BWID == b) atomicAdd(&dacc[s - b * BWID], hi16f(e));
    }
    __syncthreads();
    if (tid < BWID) {
        float d = dacc[tid];
        dinv[(size_t)tl * NN + b * BWID + tid] = d > 0.f ? 1.f / sqrtf(d) : 0.f;
    }
}

// ---------------- per-bin gather + counting sort -> CSR with precomputed wn ----------------
__global__ __launch_bounds__(256) void k_csr(
    const ull* __restrict__ dslot, const uchar* __restrict__ dcnt_,
    const ull* __restrict__ dsp, const int* __restrict__ spn,
    const float* __restrict__ dinv,
    uint* __restrict__ entries, int* __restrict__ row_ptr, int* __restrict__ cnt)
{
    __shared__ uint proc[ECAP];
    __shared__ uchar lnb[ECAP];
    __shared__ uint staged[ECAP];
    __shared__ int lcnt[BWID], loff[BWID];
    __shared__ uchar cs[256];
    __shared__ int sscan[256];
    __shared__ int extr;
    int tl = blockIdx.x / NBIN, b = blockIdx.x % NBIN, tid = threadIdx.x;
    const float* dv = dinv + (size_t)tl * NN;
    if (tid < BWID) lcnt[tid] = 0;
    cs[tid] = (tid < 250) ? dcnt_[(tl * 250 + tid) * 256 + b] : 0;
    __syncthreads();
    int c = (int)cs[tid];
    sscan[tid] = c;
    __syncthreads();
    #pragma unroll
    for (int o = 1; o < 256; o <<= 1) {
        int v = (tid >= o) ? sscan[tid - o] : 0;
        __syncthreads();
        sscan[tid] += v;
        __syncthreads();
    }
    if (tid == 0) extr = sscan[255];
    // slot processing
    for (int idx = tid; idx < 250 * LCAP; idx += 256) {
        int t = idx / LCAP, p = idx % LCAP;
        if (p < (int)cs[t]) {
            int pos = sscan[t] - (int)cs[t] + p;
            if (pos < ECAP) {
                ull ev = __builtin_nontemporal_load(
                    &dslot[((size_t)(tl * 250 + t) * NBIN + b) * LCAP + p]);
                int s = (uint)ev & 0xffff, d = ((uint)ev) >> 16;
                float wn = -dv[s] * __uint_as_float((uint)(ev >> 32)) * dv[d];
                unsigned short wb = __builtin_bit_cast(unsigned short, (f16)wn);
                proc[pos] = ((uint)wb << 16) | (uint)s;
                int ln = d - b * BWID;
                lnb[pos] = (uchar)ln;
                atomicAdd(&lcnt[ln], 1);
            }
        }
    }
    __syncthreads();
    // spills
    int nsp = spn[tl]; if (nsp > SPCAP) nsp = SPCAP;
    for (int i = tid; i < nsp; i += 256) {
        ull ev = dsp[(size_t)tl * SPCAP + i];
        int d = ((uint)ev) >> 16;
        if (d / BWID == b) {
            int pos = atomicAdd(&extr, 1);
            if (pos < ECAP) {
                int s = (uint)ev & 0xffff;
                float wn = -dv[s] * __uint_as_float((uint)(ev >> 32)) * dv[d];
                unsigned short wb = __builtin_bit_cast(unsigned short, (f16)wn);
                proc[pos] = ((uint)wb << 16) | (uint)s;
                int ln = d - b * BWID;
                lnb[pos] = (uchar)ln;
                atomicAdd(&lcnt[ln], 1);
            }
        }
    }
    __syncthreads();
    int nume = extr; if (nume > ECAP) nume = ECAP;
    if (tid == 0) {
        int run = 0;
        for (int i = 0; i < BWID; i++) { loff[i] = run; run += lcnt[i]; }
    }
    __syncthreads();
    size_t base = (size_t)(tl * NBIN + b) * ECAP;
    if (tid < BWID) {
        int n = tl * NN + b * BWID + tid;
        row_ptr[n] = (int)base + loff[tid];
        cnt[n] = lcnt[tid];
    }
    __syncthreads();
    for (int i = tid; i < nume; i += 256) {
        int p = atomicAdd(&loff[lnb[i]], 1);
        staged[p] = proc[i];
    }
    __syncthreads();
    for (int i = tid; i < nume; i += 256)
        entries[base + i] = staged[i];
}

// ---------------- gather core: 32 edges/iter, 16 loads in flight ----------------
__device__ __forceinline__ void gather64(
    const f16* __restrict__ src_mat, const uint* wnb, int mp, int j, int q,
    float& s0, float& s1)
{
    float a0[8], a1[8];
    #pragma unroll
    for (int k = 0; k < 8; k++) { a0[k] = 0.f; a1[k] = 0.f; }
    for (int e = 0; e < mp; e += 32) {
        uint ee[16], rr[16];
        #pragma unroll
        for (int k = 0; k < 16; k++) ee[k] = wnb[e + 2 * k + q];
        #pragma unroll
        for (int k = 0; k < 16; k++) rr[k] = *(const uint*)&src_mat[(size_t)(ee[k] & 0xffff) * HF + 2 * j];
        #pragma unroll
        for (int k = 0; k < 16; k++) {
            float w = hi16f(ee[k]);
            a0[k & 7] += w * lo16f(rr[k]);
            a1[k & 7] += w * hi16f(rr[k]);
        }
    }
    s0 = ((a0[0] + a0[1]) + (a0[2] + a0[3])) + ((a0[4] + a0[5]) + (a0[6] + a0[7]));
    s1 = ((a1[0] + a1[1]) + (a1[2] + a1[3])) + ((a1[4] + a1[5]) + (a1[6] + a1[7]));
    s0 += __shfl_xor(s0, 32);
    s1 += __shfl_xor(s1, 32);
}

// ---------------- propagation (h 64-wide + optional x ride-along) ----------------
__global__ __launch_bounds__(256) void k_prop(
    const f16* __restrict__ src_mat, const f16* __restrict__ base,
    f16* __restrict__ dst,
    const int* __restrict__ row_ptr, const int* __restrict__ cnt,
    const uint* __restrict__ entries,
    float alpha, float beta,
    const uint* __restrict__ xsrc, const uint* __restrict__ xbase,
    uint* __restrict__ xdst)
{
    __shared__ uint wnbuf[4][128];
    int ws = threadIdx.x >> 6, lane = threadIdx.x & 63;
    int node = blockIdx.x * 4 + ws;
    int m = cnt[node]; if (m > 128) m = 128;
    int st = row_ptr[node];
    int mp = (m + 31) & ~31;
    for (int idx = lane; idx < mp; idx += 64)
        wnbuf[ws][idx] = (idx < m) ? entries[st + idx] : 0u;
    asm volatile("s_waitcnt lgkmcnt(0)" ::: "memory");

    int j = lane & 31, q = lane >> 5;
    float s0, s1;
    gather64(src_mat, wnbuf[ws], mp, j, q, s0, s1);
    if (q == 0) {
        float r0 = alpha * s0, r1 = alpha * s1;
        if (base) {
            uint bv = *(const uint*)&base[(size_t)node * HF + 2 * j];
            r0 += beta * lo16f(bv);
            r1 += beta * hi16f(bv);
        }
        *(uint*)&dst[(size_t)node * HF + 2 * j] = pk16(r0, r1);
    }

    if (xdst) {
        float xa0 = 0.f, xa1 = 0.f;
        for (int i = lane; i < mp; i += 64) {
            uint ent = wnbuf[ws][i];
            uint xv = xsrc[ent & 0xffff];
            float wn = hi16f(ent);
            xa0 += wn * lo16f(xv);
            xa1 += wn * hi16f(xv);
        }
        #pragma unroll
        for (int o = 32; o >= 1; o >>= 1) {
            xa0 += __shfl_xor(xa0, o);
            xa1 += __shfl_xor(xa1, o);
        }
        if (lane == 0) {
            float r0 = alpha * xa0, r1 = alpha * xa1;
            if (xbase) { uint bv = xbase[node]; r0 += beta * lo16f(bv); r1 += beta * hi16f(bv); }
            xdst[node] = pk16(r0, r1);
        }
    }
}

// ---------------- final prop: Z = B0 + P(S); h' = u h + (1-u) tanh(Z) ----------------
__global__ __launch_bounds__(256) void k_prop_fin(
    const f16* __restrict__ S, const f16* __restrict__ B0,
    const f16* __restrict__ u, const float* __restrict__ h_in,
    float* __restrict__ h_out, f16* __restrict__ hA_out,
    const int* __restrict__ row_ptr, const int* __restrict__ cnt,
    const uint* __restrict__ entries)
{
    __shared__ uint wnbuf[4][128];
    int ws = threadIdx.x >> 6, lane = threadIdx.x & 63;
    int node = blockIdx.x * 4 + ws;
    int m = cnt[node]; if (m > 128) m = 128;
    int st = row_ptr[node];
    int mp = (m + 31) & ~31;
    for (int idx = lane; idx < mp; idx += 64)
        wnbuf[ws][idx] = (idx < m) ? entries[st + idx] : 0u;
    asm volatile("s_waitcnt lgkmcnt(0)" ::: "memory");

    int j = lane & 31, q = lane >> 5;
    float s0, s1;
    gather64(S, wnbuf[ws], mp, j, q, s0, s1);
    if (q == 0) {
        uint b0v = *(const uint*)&B0[(size_t)node * HF + 2 * j];
        float c0 = tanhf(s0 + lo16f(b0v));
        float c1 = tanhf(s1 + hi16f(b0v));
        uint uv = *(const uint*)&u[(size_t)node * HF + 2 * j];
        float u0 = lo16f(uv), u1 = hi16f(uv);
        float2 hv = *(const float2*)&h_in[(size_t)node * HF + 2 * j];
        float hn0 = u0 * hv.x + (1.f - u0) * c0;
        float hn1 = u1 * hv.y + (1.f - u1) * c1;
        *(float2*)&h_out[(size_t)node * HF + 2 * j] = make_float2(hn0, hn1);
        *(uint*)&hA_out[(size_t)node * HF + 2 * j] = pk16(hn0, hn1);
    }
}

// ---------------- fused r/u gates + c-gate input GEMMs ----------------
#define MFMA16(a, b, c) __builtin_amdgcn_mfma_f32_16x16x32_f16(a, b, c, 0, 0, 0)

__global__ __launch_bounds__(512) void k_ru(
    const f16* __restrict__ hA, const f16* __restrict__ t1, const f16* __restrict__ t2,
    const uint* __restrict__ xf, const uint* __restrict__ t1x, const uint* __restrict__ t2x,
    const f16* __restrict__ Wp, const f16* __restrict__ Wcp,
    const float* __restrict__ br, const float* __restrict__ bu, const float* __restrict__ bc,
    f16* __restrict__ u_out,
    f16* __restrict__ B0, f16* __restrict__ B1, f16* __restrict__ B2)
{
    __shared__ __attribute__((aligned(16))) f16 At[64][AS];
    __shared__ __attribute__((aligned(16))) f16 Ac[64][ACS];
    __shared__ f16 Ub[64][68];
    int n0 = blockIdx.x * 64;
    int tid = threadIdx.x;

    for (int idx = tid; idx < 64 * 8 * 3; idx += 512) {
        int a = idx >> 9, r = (idx >> 3) & 63, s = idx & 7;
        const f16* src = (a == 0) ? hA : (a == 1 ? t1 : t2);
        int gn = n0 + r;
        half8 v = {0, 0, 0, 0, 0, 0, 0, 0};
        if (gn < NN) v = *(const half8*)&src[(size_t)gn * HF + s * 8];
        *(half8*)&At[r][a * 64 + s * 8] = v;
    }
    for (int idx = tid; idx < 64 * 17; idx += 512) {
        int r = idx / 17, c = idx % 17;
        *(uint*)((char*)&At[r][198] + 4 * c) = 0u;
    }
    for (int idx = tid; idx < 64 * 3; idx += 512) {
        int r = idx & 63, a = idx >> 6;
        const uint* src = (a == 0) ? xf : (a == 1 ? t1x : t2x);
        int gn = n0 + r;
        uint v = 0;
        if (gn < NN) v = src[gn];
        *(uint*)&At[r][192 + 2 * a] = v;
    }
    for (int idx = tid; idx < 64; idx += 512) {
        int gn = n0 + idx;
        *(uint*)&Ac[idx][0] = (gn < NN) ? xf[gn] : 0u;
    }
    for (int idx = tid; idx < 64 * 15; idx += 512) {
        int r = idx / 15, c = idx % 15;
        *(uint*)((char*)&Ac[r][66] + 4 * c) = 0u;
    }
    __syncthreads();

    int wid = tid >> 6, lane = tid & 63;
    int mrow = (wid & 1) * 32;
    int nb0 = (wid >> 1) * 2;
    int arow = mrow + (lane & 15);
    int koff = (lane >> 4) << 3;
    floatx4 z = {0.f, 0.f, 0.f, 0.f};
    {
        floatx4 acc00 = z, acc01 = z, acc10 = z, acc11 = z;
        #pragma unroll
        for (int kb = 0; kb < 7; kb++) {
            half8 a0 = *(const half8*)&At[arow][kb * 32 + koff];
            half8 a1 = *(const half8*)&At[arow + 16][kb * 32 + koff];
            half8 b0 = *(const half8*)&Wp[(size_t)(((nb0    ) * 7 + kb) * 64 + lane) * 8];
            half8 b1 = *(const half8*)&Wp[(size_t)(((nb0 + 1) * 7 + kb) * 64 + lane) * 8];
            acc00 = MFMA16(a0, b0, acc00);
            acc10 = MFMA16(a1, b0, acc10);
            acc01 = MFMA16(a0, b1, acc01);
            acc11 = MFMA16(a1, b1, acc11);
        }
        bool isR = nb0 < 4;
        #pragma unroll
        for (int mi = 0; mi < 2; mi++) {
            #pragma unroll
            for (int ni = 0; ni < 2; ni++) {
                floatx4 a = (mi == 0) ? (ni == 0 ? acc00 : acc01) : (ni == 0 ? acc10 : acc11);
                int jj = ((nb0 + ni) * 16 + (lane & 15)) & 63;
                float bias = isR ? br[jj] : bu[jj];
                int rbase = mrow + mi * 16 + ((lane >> 4) << 2);
                #pragma unroll
                for (int e = 0; e < 4; e++) {
                    int rloc = rbase + e;
                    float s = 1.f / (1.f + __expf(-(a[e] + bias)));
                    if (isR) {
                        float hv = (float)At[rloc][jj];
                        Ac[rloc][2 + jj] = (f16)(s * hv);
                    } else {
                        Ub[rloc][jj] = (f16)s;
                    }
                }
            }
        }
    }
    __syncthreads();

    for (int idx = tid; idx < 64 * 32; idx += 512) {
        int n = idx >> 5, c = idx & 31;
        int gn = n0 + n;
        if (gn < NN) *(uint*)&u_out[(size_t)gn * HF + 2 * c] = *(uint*)&Ub[n][2 * c];
    }
    f16* Bs = &At[0][0];
    #pragma unroll
    for (int i = 0; i < 6; i++) {
        int t = wid * 6 + i;
        int nbc = t >> 2, mq = t & 3;
        int ar = mq * 16 + (lane & 15);
        floatx4 acc;
        float binit = (nbc < 4) ? bc[nbc * 16 + (lane & 15)] : 0.f;
        acc[0] = binit; acc[1] = binit; acc[2] = binit; acc[3] = binit;
        #pragma unroll
        for (int kb = 0; kb < 3; kb++) {
            half8 a = *(const half8*)&Ac[ar][kb * 32 + koff];
            half8 b = *(const half8*)&Wcp[(size_t)(((nbc * 3 + kb) * 64) + lane) * 8];
            acc = MFMA16(a, b, acc);
        }
        int rbase = mq * 16 + ((lane >> 4) << 2);
        int col = nbc * 16 + (lane & 15);
        #pragma unroll
        for (int e = 0; e < 4; e++)
            Bs[(size_t)(rbase + e) * BSS + col] = (f16)acc[e];
    }
    __syncthreads();

    for (int idx = tid; idx < 64 * 96; idx += 512) {
        int n = idx / 96, c = idx % 96;
        int gn = n0 + n;
        if (gn < NN) {
            int col = 2 * c;
            f16* Bdst = (col < 64) ? B0 : (col < 128 ? B1 : B2);
            *(uint*)&Bdst[(size_t)gn * HF + (col & 63)] = *(uint*)&Bs[(size_t)n * BSS + col];
        }
    }
}

// ---------------- host ----------------

extern "C" void kernel_launch(void* const* d_in, const int* in_sizes, int n_in,
                              void* d_out, int out_size, void* d_ws, size_t ws_size,
                              hipStream_t stream)
{
    const float* x    = (const float*)d_in[0];
    const int*   eidx = (const int*)d_in[1];
    const float* eatt = (const float*)d_in[2];
    const float* Wr   = (const float*)d_in[3];
    const float* br   = (const float*)d_in[4];
    const float* Wu   = (const float*)d_in[5];
    const float* bu   = (const float*)d_in[6];
    const float* Wc   = (const float*)d_in[7];
    const float* bc   = (const float*)d_in[8];

    char* ws = (char*)d_ws;
    size_t off = 0;
    auto alloc = [&](size_t bytes) -> void* {
        void* p = ws + off;
        off += (bytes + 255) & ~(size_t)255;
        return p;
    };
    const size_t FB = (size_t)NN * HF * 2;
    float* h_f32  = (float*)alloc((size_t)NN * HF * 4);
    f16*   hA     = (f16*)alloc(FB);                     // adjacent to h_f32 (one memset)
    f16*   t1     = (f16*)alloc(FB);
    f16*   t2     = (f16*)alloc(FB);                     // also reused as S
    f16*   u      = (f16*)alloc(FB);
    f16*   B0     = (f16*)alloc(FB);
    f16*   B1     = (f16*)alloc(FB);
    f16*   B2     = (f16*)alloc(FB);
    float* dinv   = (float*)alloc((size_t)TB * NN * 4);
    uint*  xf     = (uint*)alloc((size_t)TT * NN * 4);
    uint*  t1x    = (uint*)alloc((size_t)NN * 4);
    uint*  t2x    = (uint*)alloc((size_t)NN * 4);
    ull*   dslot  = (ull*)alloc((size_t)TB * 250 * NBIN * LCAP * 8);   // 24 MB
    uint*  sslot  = (uint*)alloc((size_t)TB * 250 * NBIN * LCAP * 4);  // 12 MB
    uchar* dcnt_  = (uchar*)alloc((size_t)TB * 250 * 256);
    uchar* scnt_  = (uchar*)alloc((size_t)TB * 250 * 256);
    ull*   dsp    = (ull*)alloc((size_t)TB * SPCAP * 8);
    uint*  ssp    = (uint*)alloc((size_t)TB * SPCAP * 4);
    int*   spz    = (int*)alloc(256);                     // spn[2] | ssn[2]
    uint*  entr   = (uint*)alloc((size_t)TB * NBIN * ECAP * 4);        // 6.1 MB
    int*   rowp   = (int*)alloc((size_t)TB * NN * 4);
    int*   cnt    = (int*)alloc((size_t)TB * NN * 4);
    f16*   Wp     = (f16*)alloc((size_t)8 * 7 * 64 * 8 * 2);
    f16*   Wcp    = (f16*)alloc((size_t)12 * 3 * 64 * 8 * 2);
    int*   spn = spz, *ssn = spz + 2;

    hipMemsetAsync(h_f32, 0, (size_t)NN * HF * 4 + FB, stream);  // h_f32 + hA
    k_prepW<<<30, 256, 0, stream>>>(Wr, Wu, Wc, Wp, Wcp);
    k_pack <<<(TT * NN + 255) / 256, 256, 0, stream>>>(x, xf);

    const int GB = (NN + 63) / 64;

    for (int qtr = 0; qtr < 4; ++qtr) {
        int t0 = qtr * TB;
        hipMemsetAsync(spz, 0, 16, stream);
        k_bin   <<<TB * 250, 256, 0, stream>>>(eidx, eatt, t0, dslot, dcnt_, sslot, scnt_,
                                               dsp, spn, ssp, ssn);
        k_degred<<<TB * NBIN, 256, 0, stream>>>(sslot, scnt_, ssp, ssn, dinv);
        k_csr   <<<TB * NBIN, 256, 0, stream>>>(dslot, dcnt_, dsp, spn, dinv, entr, rowp, cnt);

        for (int tl = 0; tl < TB; ++tl) {
            int t = t0 + tl;
            const int* rp = rowp + (size_t)tl * NN;
            const int* cp = cnt + (size_t)tl * NN;
            uint* xft = xf + (size_t)t * NN;

            // r/u Chebyshev basis on h (x basis rides along)
            k_prop<<<PBLK, 256, 0, stream>>>(hA, nullptr, t1, rp, cp, entr, 1.f,  0.f, xft, nullptr, t1x);
            k_prop<<<PBLK, 256, 0, stream>>>(t1, hA,      t2, rp, cp, entr, 2.f, -1.f, t1x, xft,     t2x);

            // gates + c-input GEMMs (B0,B1,B2)
            k_ru<<<GB, 512, 0, stream>>>(hA, t1, t2, xft, t1x, t2x, Wp, Wcp,
                                         br, bu, bc, u, B0, B1, B2);

            // S = B1 + 2*P(B2)
            k_prop<<<PBLK, 256, 0, stream>>>(B2, B1, t2, rp, cp, entr, 2.f, 1.f, nullptr, nullptr, nullptr);

            // h' = u h + (1-u) tanh(B0 + P S)
            float* hdst = (t == TT - 1) ? (float*)d_out : h_f32;
            k_prop_fin<<<PBLK, 256, 0, stream>>>(t2, B0, u, h_f32, hdst, hA, rp, cp, entr);
        }
    }
}

// Round 11
// 699.790 us; speedup vs baseline: 1.1720x; 1.1720x over previous
//
#include <hip/hip_runtime.h>

#define NN 20000
#define EE 640000
#define TT 8
#define HF 64
#define AS 232     // LDS A-tile row stride (f16) in k_ru
#define ACS 104    // LDS A_c tile row stride (f16)
#define BSS 194    // LDS B-stage row stride (f16), gcd(97,32)=1
#define PBLK 5000  // prop blocks (4 nodes each)
#define TILE 2560  // edges per k_bin tile (250 tiles/step)
#define NBIN 250   // bins (both src and dst side)
#define BWID 80    // nodes per bin
#define ECAP 3072  // per-(step,bin) entry capacity (mean 2560 + 10 sigma)
#define LCAP 24    // per-tile per-bin LDS buffer (mean 10.2; overflow path exists)

typedef _Float16 f16;
typedef unsigned int uint;
typedef unsigned char uchar;
typedef __attribute__((ext_vector_type(8))) _Float16 half8;
typedef __attribute__((ext_vector_type(4))) float floatx4;

__device__ __forceinline__ float lo16f(uint v) { return (float)__builtin_bit_cast(f16, (unsigned short)(v & 0xffff)); }
__device__ __forceinline__ float hi16f(uint v) { return (float)__builtin_bit_cast(f16, (unsigned short)(v >> 16)); }
__device__ __forceinline__ uint pk16(float a, float b) {
    unsigned short ua = __builtin_bit_cast(unsigned short, (f16)a);
    unsigned short ub = __builtin_bit_cast(unsigned short, (f16)b);
    return (uint)ua | ((uint)ub << 16);
}

// ---------------- weight packs (once per launch) ----------------
__global__ __launch_bounds__(256) void k_prepW(
    const float* __restrict__ Wr, const float* __restrict__ Wu, const float* __restrict__ Wc,
    f16* __restrict__ Wp, f16* __restrict__ Wcp)
{
    int idx = blockIdx.x * 256 + threadIdx.x;
    if (idx < 8 * 7 * 64) {
        int lane = idx & 63;
        int kb = (idx >> 6) % 7;
        int nb = (idx >> 6) / 7;
        int col = nb * 16 + (lane & 15);
        int g = col >> 6, jj = col & 63;
        const float* W = (g == 0) ? Wr : Wu;
        half8 v;
        #pragma unroll
        for (int e = 0; e < 8; e++) {
            int k = kb * 32 + ((lane >> 4) << 3) + e;
            float val = 0.f;
            if (k < 192)      { int hop = k >> 6; int i = 2 + (k & 63); val = W[(hop * 66 + i) * 64 + jj]; }
            else if (k < 198) { int q = k - 192;  int hop = q >> 1;     val = W[(hop * 66 + (q & 1)) * 64 + jj]; }
            v[e] = (f16)val;
        }
        *(half8*)&Wp[(size_t)idx * 8] = v;
        return;
    }
    int idx2 = idx - 8 * 7 * 64;
    if (idx2 >= 12 * 3 * 64) return;
    int lane = idx2 & 63;
    int kb = (idx2 >> 6) % 3;
    int nbc = (idx2 >> 6) / 3;
    int col = nbc * 16 + (lane & 15);
    int mode = col >> 6, j = col & 63;
    half8 v;
    #pragma unroll
    for (int e = 0; e < 8; e++) {
        int k = kb * 32 + ((lane >> 4) << 3) + e;
        float val = 0.f;
        if (k < 66) {
            if (mode == 0)      val = Wc[(0 * 66 + k) * 64 + j] - Wc[(2 * 66 + k) * 64 + j];
            else if (mode == 1) val = Wc[(1 * 66 + k) * 64 + j];
            else                val = Wc[(2 * 66 + k) * 64 + j];
        }
        v[e] = (f16)val;
    }
    *(half8*)&Wcp[(size_t)idx2 * 8] = v;
}

// ---------------- pack all x into f16x2 (once per launch) ----------------
__global__ __launch_bounds__(256) void k_pack(
    const float* __restrict__ x, uint* __restrict__ xf)
{
    int idx = blockIdx.x * 256 + threadIdx.x;
    if (idx < TT * NN) xf[idx] = pk16(x[2 * idx], x[2 * idx + 1]);
}

// ---------------- binning: dual (dst entries + src deg-entries), all 8 steps ----------------
__global__ __launch_bounds__(256) void k_bin(
    const int* __restrict__ eidx, const float* __restrict__ eatt,
    int* __restrict__ binptr, uint2* __restrict__ ebuf,
    int* __restrict__ sbinptr, uint* __restrict__ sbuf)
{
    __shared__ uint2 buf[NBIN][LCAP];    // 48000 B
    __shared__ uint  sbl[NBIN][LCAP];    // 24000 B
    __shared__ int lcnt[NBIN], scnt[NBIN];
    __shared__ int scan[256];
    __shared__ int gb[NBIN];
    int tid = threadIdx.x;
    if (tid < NBIN) { lcnt[tid] = 0; scnt[tid] = 0; }
    __syncthreads();
    int tl = blockIdx.x / 250, tile = blockIdx.x % 250;
    const int*   src = eidx + (size_t)tl * 2 * EE + tile * TILE;
    const int*   dst = src + EE;
    const float* w   = eatt + (size_t)tl * EE + tile * TILE;
    int* bp = binptr + tl * NBIN;
    int* sp = sbinptr + tl * NBIN;
    size_t ebase = (size_t)tl * NBIN * ECAP;
    #pragma unroll
    for (int i = 0; i < TILE / 256; i++) {
        int e = i * 256 + tid;
        int s = __builtin_nontemporal_load(&src[e]);
        int d = __builtin_nontemporal_load(&dst[e]);
        float wv = __builtin_nontemporal_load(&w[e]);
        int bin = d / BWID;
        uint2 ent = make_uint2(((uint)d << 16) | (uint)s, __float_as_uint(wv));
        int p = atomicAdd(&lcnt[bin], 1);
        if (p < LCAP) buf[bin][p] = ent;
        else {
            int gp = atomicAdd(&bp[bin], 1);
            if (gp < ECAP) ebuf[ebase + (size_t)bin * ECAP + gp] = ent;
        }
        int sbin = s / BWID;
        uint sent = (pk16(wv, 0.f) << 16) | (uint)s;
        int sq = atomicAdd(&scnt[sbin], 1);
        if (sq < LCAP) sbl[sbin][sq] = sent;
        else {
            int gp = atomicAdd(&sp[sbin], 1);
            if (gp < ECAP) sbuf[ebase + (size_t)sbin * ECAP + gp] = sent;
        }
    }
    __syncthreads();
    // ---- flush dst ----
    {
        int c = (tid < NBIN) ? (lcnt[tid] < LCAP ? lcnt[tid] : LCAP) : 0;
        scan[tid] = c;
        __syncthreads();
        #pragma unroll
        for (int o = 1; o < 256; o <<= 1) {
            int v = (tid >= o) ? scan[tid - o] : 0;
            __syncthreads();
            scan[tid] += v;
            __syncthreads();
        }
        if (c > 0) gb[tid] = atomicAdd(&bp[tid], c);
        __syncthreads();
        int total = scan[255];
        for (int i = tid; i < total; i += 256) {
            int lo = 0, hi = 255;
            #pragma unroll
            for (int it = 0; it < 8; it++) { int mid = (lo + hi) >> 1; if (scan[mid] > i) hi = mid; else lo = mid + 1; }
            int p = i - (lo ? scan[lo - 1] : 0);
            int gp = gb[lo] + p;
            if (gp < ECAP) ebuf[ebase + (size_t)lo * ECAP + gp] = buf[lo][p];
        }
    }
    __syncthreads();
    // ---- flush src ----
    {
        int c = (tid < NBIN) ? (scnt[tid] < LCAP ? scnt[tid] : LCAP) : 0;
        scan[tid] = c;
        __syncthreads();
        #pragma unroll
        for (int o = 1; o < 256; o <<= 1) {
            int v = (tid >= o) ? scan[tid - o] : 0;
            __syncthreads();
            scan[tid] += v;
            __syncthreads();
        }
        if (c > 0) gb[tid] = atomicAdd(&sp[tid], c);
        __syncthreads();
        int total = scan[255];
        for (int i = tid; i < total; i += 256) {
            int lo = 0, hi = 255;
            #pragma unroll
            for (int it = 0; it < 8; it++) { int mid = (lo + hi) >> 1; if (scan[mid] > i) hi = mid; else lo = mid + 1; }
            int p = i - (lo ? scan[lo - 1] : 0);
            int gp = gb[lo] + p;
            if (gp < ECAP) sbuf[ebase + (size_t)lo * ECAP + gp] = sbl[lo][p];
        }
    }
}

// ---------------- deg reduce: per src-bin, LDS accumulate, coalesced dinv write ----------------
__global__ __launch_bounds__(256) void k_degred(
    const uint* __restrict__ sbuf, const int* __restrict__ sbinptr,
    float* __restrict__ dinv)
{
    __shared__ float dacc[BWID];
    int tl = blockIdx.x / NBIN, b = blockIdx.x % NBIN, tid = threadIdx.x;
    int nume = sbinptr[tl * NBIN + b]; if (nume > ECAP) nume = ECAP;
    if (tid < BWID) dacc[tid] = 0.f;
    __syncthreads();
    size_t base = (size_t)(tl * NBIN + b) * ECAP;
    for (int i = tid; i < nume; i += 256) {
        uint e = sbuf[base + i];
        atomicAdd(&dacc[(e & 0xffff) - b * BWID], hi16f(e));
    }
    __syncthreads();
    if (tid < BWID) {
        float d = dacc[tid];
        dinv[(size_t)tl * NN + b * BWID + tid] = d > 0.f ? 1.f / sqrtf(d) : 0.f;
    }
}

// ---------------- per-bin counting sort -> CSR with precomputed wn ----------------
__global__ __launch_bounds__(256) void k_csr(
    const uint2* __restrict__ ebuf, const int* __restrict__ binptr,
    const float* __restrict__ dinv,
    uint* __restrict__ entries, int* __restrict__ row_ptr, int* __restrict__ cnt)
{
    __shared__ uint proc[ECAP];
    __shared__ uchar lnb[ECAP];
    __shared__ uint staged[ECAP];
    __shared__ int lcnt[BWID], loff[BWID];
    int tl = blockIdx.x / NBIN, b = blockIdx.x % NBIN, tid = threadIdx.x;
    int nume = binptr[tl * NBIN + b]; if (nume > ECAP) nume = ECAP;
    const float* dv = dinv + (size_t)tl * NN;
    size_t base = (size_t)(tl * NBIN + b) * ECAP;
    if (tid < BWID) lcnt[tid] = 0;
    __syncthreads();
    for (int i = tid; i < nume; i += 256) {
        uint2 ent = ebuf[base + i];
        int s = ent.x & 0xffff;
        int d = ent.x >> 16;
        float wv = __uint_as_float(ent.y);
        float wn = -dv[s] * wv * dv[d];
        unsigned short wb = __builtin_bit_cast(unsigned short, (f16)wn);
        proc[i] = ((uint)wb << 16) | (uint)s;
        int ln = d - b * BWID;
        lnb[i] = (uchar)ln;
        atomicAdd(&lcnt[ln], 1);
    }
    __syncthreads();
    if (tid == 0) {
        int run = 0;
        for (int i = 0; i < BWID; i++) { loff[i] = run; run += lcnt[i]; }
    }
    __syncthreads();
    if (tid < BWID) {
        int n = tl * NN + b * BWID + tid;
        row_ptr[n] = (int)base + loff[tid];
        cnt[n] = lcnt[tid];
    }
    __syncthreads();
    for (int i = tid; i < nume; i += 256) {
        int p = atomicAdd(&loff[lnb[i]], 1);
        staged[p] = proc[i];
    }
    __syncthreads();
    for (int i = tid; i < nume; i += 256)
        entries[base + i] = staged[i];
}

// ---------------- gather core: 16-stride main (8 in flight) + 8-stride tail ----------------
__device__ __forceinline__ void gather64(
    const f16* __restrict__ src_mat, const uint* wnb, int mp, int j, int q,
    float& s0, float& s1)
{
    float a0[8], a1[8];
    #pragma unroll
    for (int k = 0; k < 8; k++) { a0[k] = 0.f; a1[k] = 0.f; }
    int e = 0;
    for (; e + 16 <= mp; e += 16) {
        uint ee[8], rr[8];
        #pragma unroll
        for (int k = 0; k < 8; k++) ee[k] = wnb[e + 2 * k + q];
        #pragma unroll
        for (int k = 0; k < 8; k++) rr[k] = *(const uint*)&src_mat[(size_t)(ee[k] & 0xffff) * HF + 2 * j];
        #pragma unroll
        for (int k = 0; k < 8; k++) {
            float w = hi16f(ee[k]);
            a0[k] += w * lo16f(rr[k]);
            a1[k] += w * hi16f(rr[k]);
        }
    }
    for (; e < mp; e += 8) {
        uint ee[4], rr[4];
        #pragma unroll
        for (int k = 0; k < 4; k++) ee[k] = wnb[e + 2 * k + q];
        #pragma unroll
        for (int k = 0; k < 4; k++) rr[k] = *(const uint*)&src_mat[(size_t)(ee[k] & 0xffff) * HF + 2 * j];
        #pragma unroll
        for (int k = 0; k < 4; k++) {
            float w = hi16f(ee[k]);
            a0[k] += w * lo16f(rr[k]);
            a1[k] += w * hi16f(rr[k]);
        }
    }
    s0 = ((a0[0] + a0[1]) + (a0[2] + a0[3])) + ((a0[4] + a0[5]) + (a0[6] + a0[7]));
    s1 = ((a1[0] + a1[1]) + (a1[2] + a1[3])) + ((a1[4] + a1[5]) + (a1[6] + a1[7]));
    s0 += __shfl_xor(s0, 32);
    s1 += __shfl_xor(s1, 32);
}

// ---------------- propagation (h 64-wide + optional x ride-along) ----------------
__global__ __launch_bounds__(256) void k_prop(
    const f16* __restrict__ src_mat, const f16* __restrict__ base,
    f16* __restrict__ dst,
    const int* __restrict__ row_ptr, const int* __restrict__ cnt,
    const uint* __restrict__ entries,
    float alpha, float beta,
    const uint* __restrict__ xsrc, const uint* __restrict__ xbase,
    uint* __restrict__ xdst)
{
    __shared__ uint wnbuf[4][128];
    int ws = threadIdx.x >> 6, lane = threadIdx.x & 63;
    int node = blockIdx.x * 4 + ws;
    int m = cnt[node]; if (m > 128) m = 128;
    int st = row_ptr[node];
    int mp = (m + 7) & ~7;
    for (int idx = lane; idx < mp; idx += 64)
        wnbuf[ws][idx] = (idx < m) ? entries[st + idx] : 0u;
    asm volatile("s_waitcnt lgkmcnt(0)" ::: "memory");

    int j = lane & 31, q = lane >> 5;
    float s0, s1;
    gather64(src_mat, wnbuf[ws], mp, j, q, s0, s1);
    if (q == 0) {
        float r0 = alpha * s0, r1 = alpha * s1;
        if (base) {
            uint bv = *(const uint*)&base[(size_t)node * HF + 2 * j];
            r0 += beta * lo16f(bv);
            r1 += beta * hi16f(bv);
        }
        *(uint*)&dst[(size_t)node * HF + 2 * j] = pk16(r0, r1);
    }

    if (xdst) {
        float xa0 = 0.f, xa1 = 0.f;
        for (int i = lane; i < mp; i += 64) {
            uint ent = wnbuf[ws][i];
            uint xv = xsrc[ent & 0xffff];
            float wn = hi16f(ent);
            xa0 += wn * lo16f(xv);
            xa1 += wn * hi16f(xv);
        }
        #pragma unroll
        for (int o = 32; o >= 1; o >>= 1) {
            xa0 += __shfl_xor(xa0, o);
            xa1 += __shfl_xor(xa1, o);
        }
        if (lane == 0) {
            float r0 = alpha * xa0, r1 = alpha * xa1;
            if (xbase) { uint bv = xbase[node]; r0 += beta * lo16f(bv); r1 += beta * hi16f(bv); }
            xdst[node] = pk16(r0, r1);
        }
    }
}

// ---------------- final prop: Z = B0 + P(S); h' = u h + (1-u) tanh(Z) ----------------
__global__ __launch_bounds__(256) void k_prop_fin(
    const f16* __restrict__ S, const f16* __restrict__ B0,
    const f16* __restrict__ u, const float* __restrict__ h_in,
    float* __restrict__ h_out, f16* __restrict__ hA_out,
    const int* __restrict__ row_ptr, const int* __restrict__ cnt,
    const uint* __restrict__ entries)
{
    __shared__ uint wnbuf[4][128];
    int ws = threadIdx.x >> 6, lane = threadIdx.x & 63;
    int node = blockIdx.x * 4 + ws;
    int m = cnt[node]; if (m > 128) m = 128;
    int st = row_ptr[node];
    int mp = (m + 7) & ~7;
    for (int idx = lane; idx < mp; idx += 64)
        wnbuf[ws][idx] = (idx < m) ? entries[st + idx] : 0u;
    asm volatile("s_waitcnt lgkmcnt(0)" ::: "memory");

    int j = lane & 31, q = lane >> 5;
    float s0, s1;
    gather64(S, wnbuf[ws], mp, j, q, s0, s1);
    if (q == 0) {
        uint b0v = *(const uint*)&B0[(size_t)node * HF + 2 * j];
        float c0 = tanhf(s0 + lo16f(b0v));
        float c1 = tanhf(s1 + hi16f(b0v));
        uint uv = *(const uint*)&u[(size_t)node * HF + 2 * j];
        float u0 = lo16f(uv), u1 = hi16f(uv);
        float2 hv = *(const float2*)&h_in[(size_t)node * HF + 2 * j];
        float hn0 = u0 * hv.x + (1.f - u0) * c0;
        float hn1 = u1 * hv.y + (1.f - u1) * c1;
        *(float2*)&h_out[(size_t)node * HF + 2 * j] = make_float2(hn0, hn1);
        *(uint*)&hA_out[(size_t)node * HF + 2 * j] = pk16(hn0, hn1);
    }
}

// ---------------- fused r/u gates + c-gate input GEMMs ----------------
#define MFMA16(a, b, c) __builtin_amdgcn_mfma_f32_16x16x32_f16(a, b, c, 0, 0, 0)

__global__ __launch_bounds__(512) void k_ru(
    const f16* __restrict__ hA, const f16* __restrict__ t1, const f16* __restrict__ t2,
    const uint* __restrict__ xf, const uint* __restrict__ t1x, const uint* __restrict__ t2x,
    const f16* __restrict__ Wp, const f16* __restrict__ Wcp,
    const float* __restrict__ br, const float* __restrict__ bu, const float* __restrict__ bc,
    f16* __restrict__ u_out,
    f16* __restrict__ B0, f16* __restrict__ B1, f16* __restrict__ B2)
{
    __shared__ __attribute__((aligned(16))) f16 At[64][AS];
    __shared__ __attribute__((aligned(16))) f16 Ac[64][ACS];
    __shared__ f16 Ub[64][68];
    int n0 = blockIdx.x * 64;
    int tid = threadIdx.x;

    for (int idx = tid; idx < 64 * 8 * 3; idx += 512) {
        int a = idx >> 9, r = (idx >> 3) & 63, s = idx & 7;
        const f16* src = (a == 0) ? hA : (a == 1 ? t1 : t2);
        int gn = n0 + r;
        half8 v = {0, 0, 0, 0, 0, 0, 0, 0};
        if (gn < NN) v = *(const half8*)&src[(size_t)gn * HF + s * 8];
        *(half8*)&At[r][a * 64 + s * 8] = v;
    }
    for (int idx = tid; idx < 64 * 17; idx += 512) {
        int r = idx / 17, c = idx % 17;
        *(uint*)((char*)&At[r][198] + 4 * c) = 0u;
    }
    for (int idx = tid; idx < 64 * 3; idx += 512) {
        int r = idx & 63, a = idx >> 6;
        const uint* src = (a == 0) ? xf : (a == 1 ? t1x : t2x);
        int gn = n0 + r;
        uint v = 0;
        if (gn < NN) v = src[gn];
        *(uint*)&At[r][192 + 2 * a] = v;
    }
    for (int idx = tid; idx < 64; idx += 512) {
        int gn = n0 + idx;
        *(uint*)&Ac[idx][0] = (gn < NN) ? xf[gn] : 0u;
    }
    for (int idx = tid; idx < 64 * 15; idx += 512) {
        int r = idx / 15, c = idx % 15;
        *(uint*)((char*)&Ac[r][66] + 4 * c) = 0u;
    }
    __syncthreads();

    int wid = tid >> 6, lane = tid & 63;
    int mrow = (wid & 1) * 32;
    int nb0 = (wid >> 1) * 2;
    int arow = mrow + (lane & 15);
    int koff = (lane >> 4) << 3;
    floatx4 z = {0.f, 0.f, 0.f, 0.f};
    {
        floatx4 acc00 = z, acc01 = z, acc10 = z, acc11 = z;
        #pragma unroll
        for (int kb = 0; kb < 7; kb++) {
            half8 a0 = *(const half8*)&At[arow][kb * 32 + koff];
            half8 a1 = *(const half8*)&At[arow + 16][kb * 32 + koff];
            half8 b0 = *(const half8*)&Wp[(size_t)(((nb0    ) * 7 + kb) * 64 + lane) * 8];
            half8 b1 = *(const half8*)&Wp[(size_t)(((nb0 + 1) * 7 + kb) * 64 + lane) * 8];
            acc00 = MFMA16(a0, b0, acc00);
            acc10 = MFMA16(a1, b0, acc10);
            acc01 = MFMA16(a0, b1, acc01);
            acc11 = MFMA16(a1, b1, acc11);
        }
        bool isR = nb0 < 4;
        #pragma unroll
        for (int mi = 0; mi < 2; mi++) {
            #pragma unroll
            for (int ni = 0; ni < 2; ni++) {
                floatx4 a = (mi == 0) ? (ni == 0 ? acc00 : acc01) : (ni == 0 ? acc10 : acc11);
                int jj = ((nb0 + ni) * 16 + (lane & 15)) & 63;
                float bias = isR ? br[jj] : bu[jj];
                int rbase = mrow + mi * 16 + ((lane >> 4) << 2);
                #pragma unroll
                for (int e = 0; e < 4; e++) {
                    int rloc = rbase + e;
                    float s = 1.f / (1.f + __expf(-(a[e] + bias)));
                    if (isR) {
                        float hv = (float)At[rloc][jj];
                        Ac[rloc][2 + jj] = (f16)(s * hv);
                    } else {
                        Ub[rloc][jj] = (f16)s;
                    }
                }
            }
        }
    }
    __syncthreads();

    for (int idx = tid; idx < 64 * 32; idx += 512) {
        int n = idx >> 5, c = idx & 31;
        int gn = n0 + n;
        if (gn < NN) *(uint*)&u_out[(size_t)gn * HF + 2 * c] = *(uint*)&Ub[n][2 * c];
    }
    f16* Bs = &At[0][0];
    #pragma unroll
    for (int i = 0; i < 6; i++) {
        int t = wid * 6 + i;
        int nbc = t >> 2, mq = t & 3;
        int ar = mq * 16 + (lane & 15);
        floatx4 acc;
        float binit = (nbc < 4) ? bc[nbc * 16 + (lane & 15)] : 0.f;
        acc[0] = binit; acc[1] = binit; acc[2] = binit; acc[3] = binit;
        #pragma unroll
        for (int kb = 0; kb < 3; kb++) {
            half8 a = *(const half8*)&Ac[ar][kb * 32 + koff];
            half8 b = *(const half8*)&Wcp[(size_t)(((nbc * 3 + kb) * 64) + lane) * 8];
            acc = MFMA16(a, b, acc);
        }
        int rbase = mq * 16 + ((lane >> 4) << 2);
        int col = nbc * 16 + (lane & 15);
        #pragma unroll
        for (int e = 0; e < 4; e++)
            Bs[(size_t)(rbase + e) * BSS + col] = (f16)acc[e];
    }
    __syncthreads();

    for (int idx = tid; idx < 64 * 96; idx += 512) {
        int n = idx / 96, c = idx % 96;
        int gn = n0 + n;
        if (gn < NN) {
            int col = 2 * c;
            f16* Bdst = (col < 64) ? B0 : (col < 128 ? B1 : B2);
            *(uint*)&Bdst[(size_t)gn * HF + (col & 63)] = *(uint*)&Bs[(size_t)n * BSS + col];
        }
    }
}

// ---------------- host ----------------

extern "C" void kernel_launch(void* const* d_in, const int* in_sizes, int n_in,
                              void* d_out, int out_size, void* d_ws, size_t ws_size,
                              hipStream_t stream)
{
    const float* x    = (const float*)d_in[0];
    const int*   eidx = (const int*)d_in[1];
    const float* eatt = (const float*)d_in[2];
    const float* Wr   = (const float*)d_in[3];
    const float* br   = (const float*)d_in[4];
    const float* Wu   = (const float*)d_in[5];
    const float* bu   = (const float*)d_in[6];
    const float* Wc   = (const float*)d_in[7];
    const float* bc   = (const float*)d_in[8];

    char* ws = (char*)d_ws;
    size_t off = 0;
    auto alloc = [&](size_t bytes) -> void* {
        void* p = ws + off;
        off += (bytes + 255) & ~(size_t)255;
        return p;
    };
    const size_t FB = (size_t)NN * HF * 2;
    float* h_f32   = (float*)alloc((size_t)NN * HF * 4);
    f16*   hA      = (f16*)alloc(FB);                     // adjacent to h_f32 (one memset)
    f16*   t1      = (f16*)alloc(FB);
    f16*   t2      = (f16*)alloc(FB);                     // also reused as S
    f16*   u       = (f16*)alloc(FB);
    f16*   B0      = (f16*)alloc(FB);
    f16*   B1      = (f16*)alloc(FB);
    f16*   B2      = (f16*)alloc(FB);
    float* dinv    = (float*)alloc((size_t)TT * NN * 4);
    uint*  xf      = (uint*)alloc((size_t)TT * NN * 4);
    uint*  t1x     = (uint*)alloc((size_t)NN * 4);
    uint*  t2x     = (uint*)alloc((size_t)NN * 4);
    int*   bptr2   = (int*)alloc((size_t)2 * TT * NBIN * 4);       // binptr | sbinptr
    uint2* ebuf    = (uint2*)alloc((size_t)TT * NBIN * ECAP * 8);  // 49.2 MB
    uint*  sbuf    = (uint*)alloc((size_t)TT * NBIN * ECAP * 4);   // 24.6 MB
    uint*  entr    = (uint*)alloc((size_t)TT * NBIN * ECAP * 4);   // 24.6 MB
    int*   rowp    = (int*)alloc((size_t)TT * NN * 4);
    int*   cnt     = (int*)alloc((size_t)TT * NN * 4);
    f16*   Wp      = (f16*)alloc((size_t)8 * 7 * 64 * 8 * 2);
    f16*   Wcp     = (f16*)alloc((size_t)12 * 3 * 64 * 8 * 2);
    int* binptr = bptr2;
    int* sbinptr = bptr2 + TT * NBIN;

    hipMemsetAsync(h_f32, 0, (size_t)NN * HF * 4 + FB, stream);    // h_f32 + hA
    hipMemsetAsync(bptr2, 0, (size_t)2 * TT * NBIN * 4, stream);   // binptr + sbinptr
    k_prepW<<<30, 256, 0, stream>>>(Wr, Wu, Wc, Wp, Wcp);
    k_pack <<<(TT * NN + 255) / 256, 256, 0, stream>>>(x, xf);

    // edge phase for all 8 steps in one go
    k_bin   <<<TT * 250, 256, 0, stream>>>(eidx, eatt, binptr, ebuf, sbinptr, sbuf);
    k_degred<<<TT * NBIN, 256, 0, stream>>>(sbuf, sbinptr, dinv);
    k_csr   <<<TT * NBIN, 256, 0, stream>>>(ebuf, binptr, dinv, entr, rowp, cnt);

    const int GB = (NN + 63) / 64;

    for (int t = 0; t < TT; ++t) {
        const int* rp = rowp + (size_t)t * NN;
        const int* cp = cnt + (size_t)t * NN;
        uint* xft = xf + (size_t)t * NN;

        // r/u Chebyshev basis on h (x basis rides along)
        k_prop<<<PBLK, 256, 0, stream>>>(hA, nullptr, t1, rp, cp, entr, 1.f,  0.f, xft, nullptr, t1x);
        k_prop<<<PBLK, 256, 0, stream>>>(t1, hA,      t2, rp, cp, entr, 2.f, -1.f, t1x, xft,     t2x);

        // gates + c-input GEMMs (B0,B1,B2)
        k_ru<<<GB, 512, 0, stream>>>(hA, t1, t2, xft, t1x, t2x, Wp, Wcp,
                                     br, bu, bc, u, B0, B1, B2);

        // S = B1 + 2*P(B2)
        k_prop<<<PBLK, 256, 0, stream>>>(B2, B1, t2, rp, cp, entr, 2.f, 1.f, nullptr, nullptr, nullptr);

        // h' = u h + (1-u) tanh(B0 + P S)
        float* hdst = (t == TT - 1) ? (float*)d_out : h_f32;
        k_prop_fin<<<PBLK, 256, 0, stream>>>(t2, B0, u, h_f32, hdst, hA, rp, cp, entr);
    }
}